// Round 7
// baseline (210.075 us; speedup 1.0000x reference)
//
#include <hip/hip_runtime.h>
#include <hip/hip_bf16.h>

// Problem dims
#define NB 32
#define NT 64
#define NJ 22
#define ND 512
#define NH 8
#define NC 128
#define NDH 64
#define NR 1408   // T*N rows per (b)

typedef __attribute__((ext_vector_type(8))) short s16x8;   // 8 bf16 (4 VGPRs)
typedef __attribute__((ext_vector_type(4))) float fx4;     // MFMA accumulator

static __device__ __forceinline__ unsigned short f2bf(float f) {
    unsigned u = __builtin_bit_cast(unsigned, f);
    u += 0x7fffu + ((u >> 16) & 1u);   // RNE
    return (unsigned short)(u >> 16);
}

static __device__ __forceinline__ fx4 mfma16(s16x8 a, s16x8 b, fx4 c) {
    return __builtin_amdgcn_mfma_f32_16x16x32_bf16(a, b, c, 0, 0, 0);
}

// async global->LDS, 16B per lane. LDS dest is wave-uniform base; HW adds lane*16.
static __device__ __forceinline__ void gload16(const void* g, void* l) {
    __builtin_amdgcn_global_load_lds(
        (const __attribute__((address_space(1))) void*)g,
        (__attribute__((address_space(3))) void*)l,
        16, 0, 0);
}

// ---------------------------------------------------------------------------
// Wt[n][k] = (bf16) W[k][n], 512x512, with the chunk-XOR swizzle on k
// (chunk ^ (n & 7)). blockIdx.z selects matrix.
__global__ __launch_bounds__(256) void twconv_k(const float* __restrict__ W,
                                                unsigned short* __restrict__ Wt,
                                                long zsrc, long zdst)
{
    __shared__ float T[64][65];
    const int tid = threadIdx.x;
    W  += blockIdx.z * zsrc + (long)blockIdx.x * 64 * 512 + blockIdx.y * 64;
    Wt += blockIdx.z * zdst + (long)blockIdx.y * 64 * 512 + blockIdx.x * 64;
    const int r = tid >> 2, c0 = (tid & 3) * 16;
    #pragma unroll
    for (int i = 0; i < 4; ++i) {
        const float4 p = *reinterpret_cast<const float4*>(W + (long)r * 512 + c0 + i*4);
        T[r][c0 + i*4 + 0] = p.x; T[r][c0 + i*4 + 1] = p.y;
        T[r][c0 + i*4 + 2] = p.z; T[r][c0 + i*4 + 3] = p.w;
    }
    __syncthreads();
    unsigned short o[16];
    #pragma unroll
    for (int i = 0; i < 16; ++i) o[i] = f2bf(T[c0 + i][r]);
    const int ch0 = ((c0 >> 3) ^ (r & 7));      // c0>>3 is even; second chunk = ch0^1
    *reinterpret_cast<s16x8*>(Wt + (long)r * 512 + ch0*8)       = *reinterpret_cast<s16x8*>(o);
    *reinterpret_cast<s16x8*>(Wt + (long)r * 512 + (ch0^1)*8)   = *reinterpret_cast<s16x8*>(o + 8);
}

// ---------------------------------------------------------------------------
// bf16 GEMM, 128x128 tile, BK=64, 4 waves, 2-phase double-buffered prefetch.
// Bt is chunk-XOR swizzled bf16 in global memory, staged via global_load_lds.
// A path:
//   AF32=false: A is chunk-XOR swizzled bf16, staged via global_load_lds.
//   AF32=true:  A is RAW f32 (x or ctx). Staged global->reg (issued before
//     COMPUTE), converted + ds_write'd in swizzled form after COMPUTE (T14).
//     LDS content is identical to the AF32=false path; COMPUTE is shared.
// MODE 0: normal store. MODE 1: K-pack kt[b][h][c][dh^swz].
// MODE 2: V-pack vt[b][h][dh][c^swz].
template <typename TC, int MODE, bool AF32>
__global__ __launch_bounds__(256) void gemm128_k(
    const void* __restrict__ Av, long lda,
    const unsigned short* __restrict__ Bt,
    const float* __restrict__ bias,
    TC* __restrict__ C, long ldc,
    long jsA, long jsW, long jsB, long jsC)
{
    __shared__ unsigned short As[2][128*64];
    __shared__ unsigned short Bs[2][128*64];

    const int tid = threadIdx.x;
    const int w = tid >> 6, lane = tid & 63;
    const long j = blockIdx.z;

    // XCD-aware bijective swizzle of the (x,y) grid (nwg % 8 == 0 always here)
    const int nx = gridDim.x;
    const int nwg = nx * gridDim.y;
    int lin = blockIdx.y * nx + blockIdx.x;
    lin = (lin & 7) * (nwg >> 3) + (lin >> 3);
    const int bx = lin % nx, by = lin / nx;

    Bt   += j * jsW + (long)by * 128 * 512;
    bias += j * jsB + by * 128;
    if constexpr (MODE == 0)
        C += (long)bx * 128 * ldc + j * jsC + by * 128;

    const int srow = lane >> 3;            // 0..7
    const int scol = (lane & 7) * 8;       // element chunk * 8
    const long aoff = (long)bx * 128 * lda + j * jsA + (long)(w*8 + srow) * lda + scol;
    const float*          Ag32 = (const float*)Av + aoff;
    const unsigned short* Ag16 = (const unsigned short*)Av + aoff;
    const unsigned short* Bg = Bt + (long)(w*8 + srow) * 512 + scol;

    const int lr = lane & 15, lk = lane >> 4;
    const int wm = w >> 1, wn = w & 1;
    const int achunk = (lane & 7) ^ srow;  // swizzled LDS chunk for A ds_write

    fx4 acc[4][4] = {};
    float4 ra[4][2];                       // in-flight A f32 (AF32 path)

    auto STAGE_B = [&](int buf, int kt) {
        char* Bl = (char*)&Bs[buf][0] + w * 1024;
        #pragma unroll
        for (int it = 0; it < 4; ++it)
            gload16(Bg + (long)it * 32 * 512 + kt, Bl + it * 4096);
    };
    auto STAGE_A_LDS = [&](int buf, int kt) {     // AF32 == false
        char* Al = (char*)&As[buf][0] + w * 1024;
        #pragma unroll
        for (int it = 0; it < 4; ++it)
            gload16(Ag16 + (long)it * 32 * lda + kt, Al + it * 4096);
    };
    auto A_LOAD = [&](int kt) {                   // AF32 == true: issue loads
        #pragma unroll
        for (int it = 0; it < 4; ++it) {
            const float* p = Ag32 + (long)it * 32 * lda + kt;
            ra[it][0] = *reinterpret_cast<const float4*>(p);
            ra[it][1] = *reinterpret_cast<const float4*>(p + 4);
        }
    };
    auto A_WRITE = [&](int buf) {                 // AF32 == true: cvt + ds_write
        #pragma unroll
        for (int it = 0; it < 4; ++it) {
            unsigned short t[8];
            t[0]=f2bf(ra[it][0].x); t[1]=f2bf(ra[it][0].y);
            t[2]=f2bf(ra[it][0].z); t[3]=f2bf(ra[it][0].w);
            t[4]=f2bf(ra[it][1].x); t[5]=f2bf(ra[it][1].y);
            t[6]=f2bf(ra[it][1].z); t[7]=f2bf(ra[it][1].w);
            *reinterpret_cast<s16x8*>(
                &As[buf][(it*32 + w*8 + srow)*64 + achunk*8]) =
                *reinterpret_cast<s16x8*>(t);
        }
    };

    auto COMPUTE = [&](int buf) {
        #pragma unroll
        for (int ks = 0; ks < 2; ++ks) {
            const int cha = (ks*4 + lk) ^ (lr & 7);   // same for A and B rows
            s16x8 a[4], b[4];
            #pragma unroll
            for (int m = 0; m < 4; ++m)
                a[m] = *reinterpret_cast<const s16x8*>(&As[buf][(wm*64 + m*16 + lr)*64 + cha*8]);
            #pragma unroll
            for (int n = 0; n < 4; ++n)
                b[n] = *reinterpret_cast<const s16x8*>(&Bs[buf][(wn*64 + n*16 + lr)*64 + cha*8]);
            #pragma unroll
            for (int m = 0; m < 4; ++m)
                #pragma unroll
                for (int n = 0; n < 4; ++n)
                    acc[m][n] = mfma16(a[m], b[n], acc[m][n]);
        }
    };

    // prologue: tile 0
    if constexpr (AF32) {
        A_LOAD(0);
        STAGE_B(0, 0);
        A_WRITE(0);            // waits on A loads; B stays in flight
    } else {
        STAGE_A_LDS(0, 0);
        STAGE_B(0, 0);
    }
    __syncthreads();

    // 2-phase pipeline over 8 K-tiles
    #pragma unroll
    for (int t = 0; t < 7; ++t) {
        const int cur = t & 1;
        const int kt_next = (t + 1) * 64;
        if constexpr (AF32) {
            A_LOAD(kt_next);             // issue early
            STAGE_B(cur ^ 1, kt_next);
            COMPUTE(cur);                // hides the loads
            A_WRITE(cur ^ 1);            // cvt+write after compute
        } else {
            STAGE_A_LDS(cur ^ 1, kt_next);
            STAGE_B(cur ^ 1, kt_next);
            COMPUTE(cur);
        }
        __syncthreads();
    }
    COMPUTE(1);                 // tile 7

    // epilogue: C/D layout col=lane&15, row=(lane>>4)*4+r
    #pragma unroll
    for (int n = 0; n < 4; ++n) {
        const int col = wn*64 + n*16 + lr;
        const float bv = bias[col];
        #pragma unroll
        for (int m = 0; m < 4; ++m) {
            #pragma unroll
            for (int r = 0; r < 4; ++r) {
                const int row = wm*64 + m*16 + lk*4 + r;
                const float val = acc[m][n][r] + bv;
                if constexpr (MODE == 0) {
                    if constexpr (sizeof(TC) == 2)
                        reinterpret_cast<unsigned short*>(C)[(long)row*ldc + col] = f2bf(val);
                    else
                        reinterpret_cast<float*>(C)[(long)row*ldc + col] = val;
                } else {
                    const int grow = bx*128 + row;       // (b, c)
                    const int gcol = by*128 + col;       // (h, dh)
                    const int b = grow >> 7, c = grow & 127;
                    const int hh = gcol >> 6, dh = gcol & 63;
                    unsigned short* Cp = reinterpret_cast<unsigned short*>(C);
                    if constexpr (MODE == 1) {
                        const int dhs = (dh & 7) | ((((dh >> 3) ^ (c & 7)) & 7) << 3);
                        Cp[(((long)b*8 + hh)*128 + c)*64 + dhs] = f2bf(val);
                    } else {
                        const int cs = (c & 7) | ((((c >> 3) ^ (dh & 7)) & 15) << 3);
                        Cp[(((long)b*8 + hh)*64 + dh)*128 + cs] = f2bf(val);
                    }
                }
            }
        }
    }
}

// ---------------------------------------------------------------------------
// Attention v3: QBLK=64 (4 waves x 16 rows), 40KB LDS -> 4 blocks/CU.
// Regions: Qs[64][64] (8KB) | Ks[128][64] (16KB, becomes P[64][128] after
// QK^T) | Vs[64][128] (16KB). K/V/P chunk-XOR swizzled; only 2 barriers.
__global__ __launch_bounds__(256, 4) void attn3_k(
    const unsigned short* __restrict__ q,   // bf16 [B, NR, 512] linear
    const unsigned short* __restrict__ kt,  // bf16 [B,H,128,64] swizzled
    const unsigned short* __restrict__ vt,  // bf16 [B,H,64,128] swizzled
    unsigned short* __restrict__ o)         // bf16 [B, NR, 512] GEMM-swizzled
{
    __shared__ __align__(16) unsigned short smem[20480];   // 40960 B exactly
    unsigned short* Qs = smem;            // [64][64]
    unsigned short* Ks = smem + 4096;     // [128][64] swz; P[64][128] swz after
    unsigned short* Vs = smem + 12288;    // [64][128] swz

    const int tid = threadIdx.x;
    const int w = tid >> 6, lane = tid & 63;
    const int lr = lane & 15, lk = lane >> 4;
    const int r0 = blockIdx.x * 64;
    const int h = blockIdx.y;
    const int b = blockIdx.z;

    const unsigned short* qg = q + ((long)b*NR + r0 + w*16 + (lane>>3))*512
                                 + h*64 + (lane & 7)*8;
    const unsigned short* kg = kt + ((long)(b*8+h))*8192 + w*2048 + lane*8;
    const unsigned short* vg = vt + ((long)(b*8+h))*8192 + w*2048 + lane*8;

    // stage: Q 2 + K 4 + V 4 gload16 per wave
    gload16(qg,            (char*)Qs + w*2048);
    gload16(qg + 8*512,    (char*)Qs + w*2048 + 1024);
    #pragma unroll
    for (int it = 0; it < 4; ++it) {
        gload16(kg + it*512, (char*)Ks + w*4096 + it*1024);
        gload16(vg + it*512, (char*)Vs + w*4096 + it*1024);
    }
    __syncthreads();

    // Q fragments (wave owns rows w*16 .. w*16+15)
    s16x8 aq[2];
    #pragma unroll
    for (int kk = 0; kk < 2; ++kk)
        aq[kk] = *reinterpret_cast<const s16x8*>(&Qs[(w*16 + lr)*64 + kk*32 + lk*8]);

    // S = Q K^T  (16 x 128 per wave)
    fx4 s[8] = {};
    #pragma unroll
    for (int kk = 0; kk < 2; ++kk) {
        #pragma unroll
        for (int f = 0; f < 8; ++f) {
            const int c = f*16 + lr;
            const int chunk = (kk*4 + lk) ^ (c & 7);
            s16x8 bk = *reinterpret_cast<const s16x8*>(&Ks[c*64 + chunk*8]);
            s[f] = mfma16(aq[kk], bk, s[f]);
        }
    }
    __syncthreads();   // all waves done reading Ks; region becomes P

    unsigned short* P = Ks;   // [64][128], chunk-XOR (chunk ^ (row & 7))

    // wave-parallel softmax over C=128; P rows written are wave-own
    const float SC = 0.125f * 1.44269504088896340736f;   // scale * log2(e)
    #pragma unroll
    for (int rr = 0; rr < 4; ++rr) {
        const int row = w*16 + lk*4 + rr;
        float mx = -3.0e38f;
        #pragma unroll
        for (int f = 0; f < 8; ++f) mx = fmaxf(mx, s[f][rr]);
        #pragma unroll
        for (int off = 1; off < 16; off <<= 1) mx = fmaxf(mx, __shfl_xor(mx, off));
        float p[8]; float sum = 0.f;
        #pragma unroll
        for (int f = 0; f < 8; ++f) {
            p[f] = exp2f((s[f][rr] - mx) * SC);
            sum += p[f];
        }
        #pragma unroll
        for (int off = 1; off < 16; off <<= 1) sum += __shfl_xor(sum, off);
        const float inv = 1.0f / sum;
        #pragma unroll
        for (int f = 0; f < 8; ++f) {
            const int cg = f*16 + lr;
            P[row*128 + (((cg >> 3) ^ (row & 7)) << 3) + (cg & 7)] = f2bf(p[f] * inv);
        }
    }
    // no barrier: wave reads back only its own P rows

    // O = P V  (16 x 64 per wave, K = 128)
    fx4 oacc[4] = {};
    #pragma unroll
    for (int kt4 = 0; kt4 < 4; ++kt4) {
        const int prow = w*16 + lr;
        s16x8 ap = *reinterpret_cast<const s16x8*>(
            &P[prow*128 + (((kt4*4 + lk) ^ (prow & 7)) << 3)]);
        #pragma unroll
        for (int bn = 0; bn < 4; ++bn) {
            const int dh = bn*16 + lr;
            const int chunk = (kt4*4 + lk) ^ (dh & 7);
            s16x8 bv = *reinterpret_cast<const s16x8*>(&Vs[dh*128 + chunk*8]);
            oacc[bn] = mfma16(ap, bv, oacc[bn]);
        }
    }

    // store O with GEMM chunk-XOR swizzle (row & 7 on the 8-elem chunk index)
    unsigned short* ob = o + ((long)b*NR + r0)*512 + h*64;
    #pragma unroll
    for (int bn = 0; bn < 4; ++bn)
        #pragma unroll
        for (int rr = 0; rr < 4; ++rr) {
            const int row = w*16 + lk*4 + rr;
            const int colg = bn*16 + lr;
            const int ch = ((colg >> 3) ^ (row & 7));
            ob[(long)row*512 + ch*8 + (lr & 7)] = f2bf(oacc[bn][rr]);
        }
}

extern "C" void kernel_launch(void* const* d_in, const int* in_sizes, int n_in,
                              void* d_out, int out_size, void* d_ws, size_t ws_size,
                              hipStream_t stream)
{
    const float* x    = (const float*)d_in[0];
    const float* ctx  = (const float*)d_in[1];
    const float* Wq   = (const float*)d_in[2];
    const float* bq   = (const float*)d_in[3];
    const float* Wk   = (const float*)d_in[4];
    const float* bk   = (const float*)d_in[5];
    const float* Wv   = (const float*)d_in[6];
    const float* bv   = (const float*)d_in[7];
    const float* Wout = (const float*)d_in[8];
    const float* bout = (const float*)d_in[9];
    float* out = (float*)d_out;

    const size_t NX  = (size_t)45056 * 512;   // q / o elements
    const size_t NKV = (size_t)4096 * 512;    // k / v elements
    const size_t NW  = (size_t)512 * 512;     // one weight matrix

    unsigned short* qbf   = (unsigned short*)d_ws;     // linear
    unsigned short* obf   = qbf   + NX;                // GEMM-swizzled
    unsigned short* ktp   = obf   + NX;                // packed swizzled K
    unsigned short* vtp   = ktp   + NKV;               // packed swizzled V^T
    unsigned short* WqT   = vtp   + NKV;               // 22 matrices, [n][k] swizzled
    unsigned short* WkT   = WqT   + 22 * NW;
    unsigned short* WvT   = WkT   + NW;
    unsigned short* WoutT = WvT   + NW;

    // 1) weight transpose-converts (chunk-XOR swizzled bf16)
    twconv_k<<<dim3(8, 8, 22), 256, 0, stream>>>(Wq,   WqT,   (long)NW, (long)NW);
    twconv_k<<<dim3(8, 8, 1),  256, 0, stream>>>(Wk,   WkT,   0, 0);
    twconv_k<<<dim3(8, 8, 1),  256, 0, stream>>>(Wv,   WvT,   0, 0);
    twconv_k<<<dim3(8, 8, 1),  256, 0, stream>>>(Wout, WoutT, 0, 0);

    // 2) Q projection: reads RAW f32 x (convert fused into A-stage)
    gemm128_k<unsigned short, 0, true><<<dim3(16, 4, NJ), 256, 0, stream>>>(
        x, (long)NJ*ND, WqT, bq, qbf, (long)NJ*ND,
        (long)ND, (long)NW, (long)ND, (long)ND);

    // 3,4) K/V projections: read RAW f32 ctx; epilogue writes attn-packed layouts
    gemm128_k<unsigned short, 1, true><<<dim3(32, 4, 1), 256, 0, stream>>>(
        ctx, ND, WkT, bk, ktp, ND, 0, 0, 0, 0);
    gemm128_k<unsigned short, 2, true><<<dim3(32, 4, 1), 256, 0, stream>>>(
        ctx, ND, WvT, bv, vtp, ND, 0, 0, 0, 0);

    // 5) fused attention: one block per (64-row q-tile, h, b)
    attn3_k<<<dim3(NR/64, NH, NB), 256, 0, stream>>>(qbf, ktp, vtp, obf);

    // 6) output projection: bf16 A (pre-swizzled by attn3), f32 output
    gemm128_k<float, 0, false><<<dim3(45056/128, 4, 1), 256, 0, stream>>>(
        obf, ND, WoutT, bout, out, ND, 0, 0, 0, 0);
}

// Round 8
// 189.001 us; speedup vs baseline: 1.1115x; 1.1115x over previous
//
#include <hip/hip_runtime.h>
#include <hip/hip_bf16.h>

// Problem dims
#define NB 32
#define NT 64
#define NJ 22
#define ND 512
#define NH 8
#define NC 128
#define NDH 64
#define NR 1408   // T*N rows per (b)

typedef __attribute__((ext_vector_type(8))) short s16x8;   // 8 bf16 (4 VGPRs)
typedef __attribute__((ext_vector_type(4))) float fx4;     // MFMA accumulator

static __device__ __forceinline__ unsigned short f2bf(float f) {
    unsigned u = __builtin_bit_cast(unsigned, f);
    u += 0x7fffu + ((u >> 16) & 1u);   // RNE
    return (unsigned short)(u >> 16);
}

static __device__ __forceinline__ fx4 mfma16(s16x8 a, s16x8 b, fx4 c) {
    return __builtin_amdgcn_mfma_f32_16x16x32_bf16(a, b, c, 0, 0, 0);
}

// async global->LDS, 16B per lane. LDS dest is wave-uniform base; HW adds lane*16.
static __device__ __forceinline__ void gload16(const void* g, void* l) {
    __builtin_amdgcn_global_load_lds(
        (const __attribute__((address_space(1))) void*)g,
        (__attribute__((address_space(3))) void*)l,
        16, 0, 0);
}

// ---------------------------------------------------------------------------
// Merged f32->bf16 convert with chunk-XOR swizzle baked into the destination.
// Blocks [0, 11264) handle x (key on flat_row/22 = bt, matching the Q-proj's
// lda=NJ*512 tile rows); blocks [11264, 12288) handle ctx (key on flat_row).
__global__ __launch_bounds__(256) void convswz_all_k(
    const float* __restrict__ x, const float* __restrict__ ctx,
    unsigned short* __restrict__ xbf, unsigned short* __restrict__ cbf)
{
    const long bid = blockIdx.x;
    const float* src; unsigned short* dst; long i; int key;
    if (bid < 11264) {
        i = (bid * 256 + threadIdx.x) * 8;
        src = x; dst = xbf;
        key = (int)(((unsigned)(i >> 9) / 22u) & 7u);
    } else {
        i = ((bid - 11264) * 256 + threadIdx.x) * 8;
        src = ctx; dst = cbf;
        key = (int)(((unsigned)(i >> 9)) & 7u);
    }
    const int c = (int)((i >> 3) & 7);
    const long j = (i & ~63L) | ((long)(c ^ key) << 3);
    const float4 a = *reinterpret_cast<const float4*>(src + i);
    const float4 b = *reinterpret_cast<const float4*>(src + i + 4);
    unsigned short t[8];
    t[0]=f2bf(a.x); t[1]=f2bf(a.y); t[2]=f2bf(a.z); t[3]=f2bf(a.w);
    t[4]=f2bf(b.x); t[5]=f2bf(b.y); t[6]=f2bf(b.z); t[7]=f2bf(b.w);
    *reinterpret_cast<s16x8*>(dst + j) = *reinterpret_cast<s16x8*>(t);
}

// ---------------------------------------------------------------------------
// Wt[n][k] = (bf16) W[k][n], 512x512, chunk-XOR swizzle on k (chunk ^ (n&7)).
// All 25 weight matrices in one launch: z<22 -> Wq[z]; 22 Wk; 23 Wv; 24 Wout.
__global__ __launch_bounds__(256) void twconv_all_k(
    const float* __restrict__ Wq, const float* __restrict__ Wk,
    const float* __restrict__ Wv, const float* __restrict__ Wout,
    unsigned short* __restrict__ WqT, unsigned short* __restrict__ WkT,
    unsigned short* __restrict__ WvT, unsigned short* __restrict__ WoutT)
{
    __shared__ float T[64][65];
    const int z = blockIdx.z;
    const float* W; unsigned short* Wt;
    if (z < 22)       { W = Wq + (long)z * 262144; Wt = WqT + (long)z * 262144; }
    else if (z == 22) { W = Wk;   Wt = WkT; }
    else if (z == 23) { W = Wv;   Wt = WvT; }
    else              { W = Wout; Wt = WoutT; }

    const int tid = threadIdx.x;
    W  += (long)blockIdx.x * 64 * 512 + blockIdx.y * 64;
    Wt += (long)blockIdx.y * 64 * 512 + blockIdx.x * 64;
    const int r = tid >> 2, c0 = (tid & 3) * 16;
    #pragma unroll
    for (int i = 0; i < 4; ++i) {
        const float4 p = *reinterpret_cast<const float4*>(W + (long)r * 512 + c0 + i*4);
        T[r][c0 + i*4 + 0] = p.x; T[r][c0 + i*4 + 1] = p.y;
        T[r][c0 + i*4 + 2] = p.z; T[r][c0 + i*4 + 3] = p.w;
    }
    __syncthreads();
    unsigned short o[16];
    #pragma unroll
    for (int i = 0; i < 16; ++i) o[i] = f2bf(T[c0 + i][r]);
    const int ch0 = ((c0 >> 3) ^ (r & 7));      // c0>>3 even; second chunk = ch0^1
    *reinterpret_cast<s16x8*>(Wt + (long)r * 512 + ch0*8)     = *reinterpret_cast<s16x8*>(o);
    *reinterpret_cast<s16x8*>(Wt + (long)r * 512 + (ch0^1)*8) = *reinterpret_cast<s16x8*>(o + 8);
}

// ---------------------------------------------------------------------------
// bf16 GEMM, 128x128 tile, BK=64, 4 waves, 2-phase double-buffered prefetch.
// A and Bt chunk-XOR swizzled in global memory; LDS linear (global_load_lds),
// ds_read applies the same XOR -> conflict-free (verified 0 in R7 PMC).
// MODE 0: normal store.
// MODE 3: merged K/V projection. Grid y=8: by 0-3 -> K-pack kt[b][h][c][dh^swz]
//         from (Bt,bias)->C; by 4-7 -> V-pack vt[b][h][dh][c^swz] from
//         (Bt2,bias2)->C2. Shared A (ctx).
template <typename TC, int MODE>
__global__ __launch_bounds__(256) void gemm128_k(
    const unsigned short* __restrict__ A, long lda,
    const unsigned short* __restrict__ Bt,
    const float* __restrict__ bias,
    TC* __restrict__ C, long ldc,
    long jsA, long jsW, long jsB, long jsC,
    const unsigned short* __restrict__ Bt2,
    const float* __restrict__ bias2,
    TC* __restrict__ C2)
{
    __shared__ unsigned short As[2][128*64];
    __shared__ unsigned short Bs[2][128*64];

    const int tid = threadIdx.x;
    const int w = tid >> 6, lane = tid & 63;
    const long j = blockIdx.z;

    // XCD-aware bijective swizzle of the (x,y) grid (nwg % 8 == 0 always here)
    const int nx = gridDim.x;
    const int nwg = nx * gridDim.y;
    int lin = blockIdx.y * nx + blockIdx.x;
    lin = (lin & 7) * (nwg >> 3) + (lin >> 3);
    const int bx = lin % nx, by = lin / nx;

    int kv = 0;        // 1 = K-pack, 2 = V-pack (MODE 3 epilogue select)
    int byv = by;
    if constexpr (MODE == 3) {
        if (by >= 4) { kv = 2; byv = by - 4; Bt = Bt2; bias = bias2; C = C2; }
        else         { kv = 1; }
    }

    A    += (long)bx * 128 * lda + j * jsA;
    Bt   += j * jsW + (long)byv * 128 * 512;
    bias += j * jsB + byv * 128;
    if constexpr (MODE == 0)
        C += (long)bx * 128 * ldc + j * jsC + byv * 128;

    const int srow = lane >> 3;
    const int scol = (lane & 7) * 8;
    const unsigned short* Ag = A  + (long)(w*8 + srow) * lda + scol;
    const unsigned short* Bg = Bt + (long)(w*8 + srow) * 512 + scol;

    const int lr = lane & 15, lk = lane >> 4;
    const int wm = w >> 1, wn = w & 1;

    fx4 acc[4][4] = {};

    auto STAGE = [&](int buf, int kt) {
        char* Al = (char*)&As[buf][0] + w * 1024;
        char* Bl = (char*)&Bs[buf][0] + w * 1024;
        #pragma unroll
        for (int it = 0; it < 4; ++it)
            gload16(Ag + (long)it * 32 * lda + kt, Al + it * 4096);
        #pragma unroll
        for (int it = 0; it < 4; ++it)
            gload16(Bg + (long)it * 32 * 512 + kt, Bl + it * 4096);
    };

    auto COMPUTE = [&](int buf) {
        #pragma unroll
        for (int ks = 0; ks < 2; ++ks) {
            const int cha = (ks*4 + lk) ^ (lr & 7);   // same for A and B rows
            s16x8 a[4], b[4];
            #pragma unroll
            for (int m = 0; m < 4; ++m)
                a[m] = *reinterpret_cast<const s16x8*>(&As[buf][(wm*64 + m*16 + lr)*64 + cha*8]);
            #pragma unroll
            for (int n = 0; n < 4; ++n)
                b[n] = *reinterpret_cast<const s16x8*>(&Bs[buf][(wn*64 + n*16 + lr)*64 + cha*8]);
            #pragma unroll
            for (int m = 0; m < 4; ++m)
                #pragma unroll
                for (int n = 0; n < 4; ++n)
                    acc[m][n] = mfma16(a[m], b[n], acc[m][n]);
        }
    };

    // 2-phase pipeline over 8 K-tiles
    STAGE(0, 0);
    __syncthreads();            // drains vmcnt(0): tile 0 in LDS
    #pragma unroll
    for (int t = 0; t < 7; ++t) {
        const int cur = t & 1;
        STAGE(cur ^ 1, (t + 1) * 64);   // issue next tile's loads first
        COMPUTE(cur);                   // MFMA on current tile hides the loads
        __syncthreads();                // drain next-tile loads + reads of cur
    }
    COMPUTE(1);                 // tile 7

    // epilogue: C/D layout col=lane&15, row=(lane>>4)*4+r
    #pragma unroll
    for (int n = 0; n < 4; ++n) {
        const int col = wn*64 + n*16 + lr;
        const float bv = bias[col];
        #pragma unroll
        for (int m = 0; m < 4; ++m) {
            #pragma unroll
            for (int r = 0; r < 4; ++r) {
                const int row = wm*64 + m*16 + lk*4 + r;
                const float val = acc[m][n][r] + bv;
                if constexpr (MODE == 0) {
                    if constexpr (sizeof(TC) == 2)
                        reinterpret_cast<unsigned short*>(C)[(long)row*ldc + col] = f2bf(val);
                    else
                        reinterpret_cast<float*>(C)[(long)row*ldc + col] = val;
                } else {
                    const int grow = bx*128 + row;       // (b, c)
                    const int gcol = byv*128 + col;      // (h, dh)
                    const int b = grow >> 7, c = grow & 127;
                    const int hh = gcol >> 6, dh = gcol & 63;
                    unsigned short* Cp = reinterpret_cast<unsigned short*>(C);
                    if (kv == 1) {
                        const int dhs = (dh & 7) | ((((dh >> 3) ^ (c & 7)) & 7) << 3);
                        Cp[(((long)b*8 + hh)*128 + c)*64 + dhs] = f2bf(val);
                    } else {
                        const int cs = (c & 7) | ((((c >> 3) ^ (dh & 7)) & 15) << 3);
                        Cp[(((long)b*8 + hh)*64 + dh)*128 + cs] = f2bf(val);
                    }
                }
            }
        }
    }
}

// ---------------------------------------------------------------------------
// Attention v3: QBLK=64 (4 waves x 16 rows), 40KB LDS -> 4 blocks/CU.
// Regions: Qs[64][64] (8KB) | Ks[128][64] (16KB, becomes P[64][128] after
// QK^T) | Vs[64][128] (16KB). K/V/P chunk-XOR swizzled; only 2 barriers.
// T5: setprio(1) around the MFMA clusters (multi-block CU, phase-diverse).
__global__ __launch_bounds__(256, 4) void attn3_k(
    const unsigned short* __restrict__ q,   // bf16 [B, NR, 512] linear
    const unsigned short* __restrict__ kt,  // bf16 [B,H,128,64] swizzled
    const unsigned short* __restrict__ vt,  // bf16 [B,H,64,128] swizzled
    unsigned short* __restrict__ o)         // bf16 [B, NR, 512] GEMM-swizzled
{
    __shared__ __align__(16) unsigned short smem[20480];   // 40960 B exactly
    unsigned short* Qs = smem;            // [64][64]
    unsigned short* Ks = smem + 4096;     // [128][64] swz; P[64][128] swz after
    unsigned short* Vs = smem + 12288;    // [64][128] swz

    const int tid = threadIdx.x;
    const int w = tid >> 6, lane = tid & 63;
    const int lr = lane & 15, lk = lane >> 4;
    const int r0 = blockIdx.x * 64;
    const int h = blockIdx.y;
    const int b = blockIdx.z;

    const unsigned short* qg = q + ((long)b*NR + r0 + w*16 + (lane>>3))*512
                                 + h*64 + (lane & 7)*8;
    const unsigned short* kg = kt + ((long)(b*8+h))*8192 + w*2048 + lane*8;
    const unsigned short* vg = vt + ((long)(b*8+h))*8192 + w*2048 + lane*8;

    // stage: Q 2 + K 4 + V 4 gload16 per wave
    gload16(qg,            (char*)Qs + w*2048);
    gload16(qg + 8*512,    (char*)Qs + w*2048 + 1024);
    #pragma unroll
    for (int it = 0; it < 4; ++it) {
        gload16(kg + it*512, (char*)Ks + w*4096 + it*1024);
        gload16(vg + it*512, (char*)Vs + w*4096 + it*1024);
    }
    __syncthreads();

    // Q fragments (wave owns rows w*16 .. w*16+15)
    s16x8 aq[2];
    #pragma unroll
    for (int kk = 0; kk < 2; ++kk)
        aq[kk] = *reinterpret_cast<const s16x8*>(&Qs[(w*16 + lr)*64 + kk*32 + lk*8]);

    // S = Q K^T  (16 x 128 per wave)
    fx4 s[8] = {};
    __builtin_amdgcn_s_setprio(1);
    #pragma unroll
    for (int kk = 0; kk < 2; ++kk) {
        #pragma unroll
        for (int f = 0; f < 8; ++f) {
            const int c = f*16 + lr;
            const int chunk = (kk*4 + lk) ^ (c & 7);
            s16x8 bk = *reinterpret_cast<const s16x8*>(&Ks[c*64 + chunk*8]);
            s[f] = mfma16(aq[kk], bk, s[f]);
        }
    }
    __builtin_amdgcn_s_setprio(0);
    __syncthreads();   // all waves done reading Ks; region becomes P

    unsigned short* P = Ks;   // [64][128], chunk-XOR (chunk ^ (row & 7))

    // wave-parallel softmax over C=128; P rows written are wave-own
    const float SC = 0.125f * 1.44269504088896340736f;   // scale * log2(e)
    #pragma unroll
    for (int rr = 0; rr < 4; ++rr) {
        const int row = w*16 + lk*4 + rr;
        float mx = -3.0e38f;
        #pragma unroll
        for (int f = 0; f < 8; ++f) mx = fmaxf(mx, s[f][rr]);
        #pragma unroll
        for (int off = 1; off < 16; off <<= 1) mx = fmaxf(mx, __shfl_xor(mx, off));
        float p[8]; float sum = 0.f;
        #pragma unroll
        for (int f = 0; f < 8; ++f) {
            p[f] = exp2f((s[f][rr] - mx) * SC);
            sum += p[f];
        }
        #pragma unroll
        for (int off = 1; off < 16; off <<= 1) sum += __shfl_xor(sum, off);
        const float inv = 1.0f / sum;
        #pragma unroll
        for (int f = 0; f < 8; ++f) {
            const int cg = f*16 + lr;
            P[row*128 + (((cg >> 3) ^ (row & 7)) << 3) + (cg & 7)] = f2bf(p[f] * inv);
        }
    }
    // no barrier: wave reads back only its own P rows

    // O = P V  (16 x 64 per wave, K = 128)
    fx4 oacc[4] = {};
    __builtin_amdgcn_s_setprio(1);
    #pragma unroll
    for (int kt4 = 0; kt4 < 4; ++kt4) {
        const int prow = w*16 + lr;
        s16x8 ap = *reinterpret_cast<const s16x8*>(
            &P[prow*128 + (((kt4*4 + lk) ^ (prow & 7)) << 3)]);
        #pragma unroll
        for (int bn = 0; bn < 4; ++bn) {
            const int dh = bn*16 + lr;
            const int chunk = (kt4*4 + lk) ^ (dh & 7);
            s16x8 bv = *reinterpret_cast<const s16x8*>(&Vs[dh*128 + chunk*8]);
            oacc[bn] = mfma16(ap, bv, oacc[bn]);
        }
    }
    __builtin_amdgcn_s_setprio(0);

    // store O with GEMM chunk-XOR swizzle (row & 7 on the 8-elem chunk index)
    unsigned short* ob = o + ((long)b*NR + r0)*512 + h*64;
    #pragma unroll
    for (int bn = 0; bn < 4; ++bn)
        #pragma unroll
        for (int rr = 0; rr < 4; ++rr) {
            const int row = w*16 + lk*4 + rr;
            const int colg = bn*16 + lr;
            const int ch = ((colg >> 3) ^ (row & 7));
            ob[(long)row*512 + ch*8 + (lr & 7)] = f2bf(oacc[bn][rr]);
        }
}

extern "C" void kernel_launch(void* const* d_in, const int* in_sizes, int n_in,
                              void* d_out, int out_size, void* d_ws, size_t ws_size,
                              hipStream_t stream)
{
    const float* x    = (const float*)d_in[0];
    const float* ctx  = (const float*)d_in[1];
    const float* Wq   = (const float*)d_in[2];
    const float* bq   = (const float*)d_in[3];
    const float* Wk   = (const float*)d_in[4];
    const float* bk   = (const float*)d_in[5];
    const float* Wv   = (const float*)d_in[6];
    const float* bv   = (const float*)d_in[7];
    const float* Wout = (const float*)d_in[8];
    const float* bout = (const float*)d_in[9];
    float* out = (float*)d_out;

    const size_t NX  = (size_t)45056 * 512;   // x / q / o elements
    const size_t NKV = (size_t)4096 * 512;    // ctx / k / v elements
    const size_t NW  = (size_t)512 * 512;     // one weight matrix

    unsigned short* xbf   = (unsigned short*)d_ws;     // also obf (both GEMM-swizzled)
    unsigned short* qbf   = xbf   + NX;                // linear
    unsigned short* cbf   = qbf   + NX;                // ctx bf16, GEMM-swizzled
    unsigned short* ktp   = cbf   + NKV;               // packed swizzled K
    unsigned short* vtp   = ktp   + NKV;               // packed swizzled V^T
    unsigned short* WqT   = vtp   + NKV;               // 22 matrices, [n][k] swizzled
    unsigned short* WkT   = WqT   + 22 * NW;
    unsigned short* WvT   = WkT   + NW;
    unsigned short* WoutT = WvT   + NW;
    unsigned short* obf   = xbf;

    // 1) converts: x + ctx in one launch; all 25 weights in one launch
    convswz_all_k<<<dim3(12288), 256, 0, stream>>>(x, ctx, xbf, cbf);
    twconv_all_k<<<dim3(8, 8, 25), 256, 0, stream>>>(
        Wq, Wk, Wv, Wout, WqT, WkT, WvT, WoutT);

    // 2) Q projection: per-joint (M=2048 rows, row stride NJ*ND)
    gemm128_k<unsigned short, 0><<<dim3(16, 4, NJ), 256, 0, stream>>>(
        xbf, (long)NJ*ND, WqT, bq, qbf, (long)NJ*ND,
        (long)ND, (long)NW, (long)ND, (long)ND,
        nullptr, nullptr, nullptr);

    // 3) merged K+V projection: M = 4096, grid y=8 (0-3 K-pack, 4-7 V-pack)
    gemm128_k<unsigned short, 3><<<dim3(32, 8, 1), 256, 0, stream>>>(
        cbf, ND, WkT, bk, ktp, ND, 0, 0, 0, 0,
        WvT, bv, vtp);

    // 4) fused attention: one block per (64-row q-tile, h, b)
    attn3_k<<<dim3(NR/64, NH, NB), 256, 0, stream>>>(qbf, ktp, vtp, obf);

    // 5) output projection: bf16 A (pre-swizzled by attn3), f32 output
    gemm128_k<float, 0><<<dim3(45056/128, 4, 1), 256, 0, stream>>>(
        obf, ND, WoutT, bout, out, ND, 0, 0, 0, 0,
        nullptr, nullptr, nullptr);
}

// Round 9
// 182.440 us; speedup vs baseline: 1.1515x; 1.0360x over previous
//
#include <hip/hip_runtime.h>
#include <hip/hip_bf16.h>

// Problem dims
#define NB 32
#define NT 64
#define NJ 22
#define ND 512
#define NH 8
#define NC 128
#define NDH 64
#define NR 1408   // T*N rows per (b)

typedef __attribute__((ext_vector_type(8))) short s16x8;   // 8 bf16 (4 VGPRs)
typedef __attribute__((ext_vector_type(4))) float fx4;     // MFMA accumulator

static __device__ __forceinline__ unsigned short f2bf(float f) {
    unsigned u = __builtin_bit_cast(unsigned, f);
    u += 0x7fffu + ((u >> 16) & 1u);   // RNE
    return (unsigned short)(u >> 16);
}

static __device__ __forceinline__ fx4 mfma16(s16x8 a, s16x8 b, fx4 c) {
    return __builtin_amdgcn_mfma_f32_16x16x32_bf16(a, b, c, 0, 0, 0);
}

// async global->LDS, 16B per lane. LDS dest is wave-uniform base; HW adds lane*16.
static __device__ __forceinline__ void gload16(const void* g, void* l) {
    __builtin_amdgcn_global_load_lds(
        (const __attribute__((address_space(1))) void*)g,
        (__attribute__((address_space(3))) void*)l,
        16, 0, 0);
}

// DPP row_ror:<N> over the 16-lane row (reduction step, no LDS traffic)
template <int CTRL>
static __device__ __forceinline__ float ror16(float v) {
    return __builtin_bit_cast(float,
        __builtin_amdgcn_update_dpp(0, __builtin_bit_cast(int, v),
                                    CTRL, 0xf, 0xf, true));
}

// ---------------------------------------------------------------------------
// ONE launch for all input preprocessing.
// Blocks [0,1600):        weight transpose-convert, 25 matrices x (8x8) tiles.
//   Wt[n][k] = bf16 W[k][n], chunk-XOR swizzle on k (chunk ^ (n&7)).
// Blocks [1600,2624):     ctx f32->bf16, chunk-XOR key = flat_row & 7.
// Blocks [2624,13888):    x   f32->bf16, chunk-XOR key = (flat_row/22) & 7
//   (matches the Q-proj's lda=NJ*512 tile rows).
__global__ __launch_bounds__(256) void conv_all_k(
    const float* __restrict__ x, const float* __restrict__ ctx,
    const float* __restrict__ Wq, const float* __restrict__ Wk,
    const float* __restrict__ Wv, const float* __restrict__ Wout,
    unsigned short* __restrict__ xbf, unsigned short* __restrict__ cbf,
    unsigned short* __restrict__ WqT, unsigned short* __restrict__ WkT,
    unsigned short* __restrict__ WvT, unsigned short* __restrict__ WoutT)
{
    __shared__ float T[64][65];
    const long bid = blockIdx.x;
    const int tid = threadIdx.x;

    if (bid < 1600) {
        // ---- weight transpose-convert ----
        const int z = (int)(bid >> 6);
        const int rem = (int)(bid & 63);
        const int tbx = rem >> 3, tby = rem & 7;
        const float* W; unsigned short* Wt;
        if (z < 22)       { W = Wq + (long)z * 262144; Wt = WqT + (long)z * 262144; }
        else if (z == 22) { W = Wk;   Wt = WkT; }
        else if (z == 23) { W = Wv;   Wt = WvT; }
        else              { W = Wout; Wt = WoutT; }
        W  += (long)tbx * 64 * 512 + tby * 64;
        Wt += (long)tby * 64 * 512 + tbx * 64;
        const int r = tid >> 2, c0 = (tid & 3) * 16;
        #pragma unroll
        for (int i = 0; i < 4; ++i) {
            const float4 p = *reinterpret_cast<const float4*>(W + (long)r * 512 + c0 + i*4);
            T[r][c0 + i*4 + 0] = p.x; T[r][c0 + i*4 + 1] = p.y;
            T[r][c0 + i*4 + 2] = p.z; T[r][c0 + i*4 + 3] = p.w;
        }
        __syncthreads();
        unsigned short o[16];
        #pragma unroll
        for (int i = 0; i < 16; ++i) o[i] = f2bf(T[c0 + i][r]);
        const int ch0 = ((c0 >> 3) ^ (r & 7));
        *reinterpret_cast<s16x8*>(Wt + (long)r * 512 + ch0*8)     = *reinterpret_cast<s16x8*>(o);
        *reinterpret_cast<s16x8*>(Wt + (long)r * 512 + (ch0^1)*8) = *reinterpret_cast<s16x8*>(o + 8);
        return;
    }

    // ---- activation converts ----
    const float* src; unsigned short* dst; long i; int key;
    if (bid < 2624) {
        i = ((bid - 1600) * 256 + tid) * 8;
        src = ctx; dst = cbf;
        key = (int)(((unsigned)(i >> 9)) & 7u);
    } else {
        i = ((bid - 2624) * 256 + tid) * 8;
        src = x; dst = xbf;
        key = (int)(((unsigned)(i >> 9) / 22u) & 7u);
    }
    const int c = (int)((i >> 3) & 7);
    const long jj = (i & ~63L) | ((long)(c ^ key) << 3);
    const float4 a = *reinterpret_cast<const float4*>(src + i);
    const float4 b = *reinterpret_cast<const float4*>(src + i + 4);
    unsigned short t[8];
    t[0]=f2bf(a.x); t[1]=f2bf(a.y); t[2]=f2bf(a.z); t[3]=f2bf(a.w);
    t[4]=f2bf(b.x); t[5]=f2bf(b.y); t[6]=f2bf(b.z); t[7]=f2bf(b.w);
    *reinterpret_cast<s16x8*>(dst + jj) = *reinterpret_cast<s16x8*>(t);
}

// ---------------------------------------------------------------------------
// bf16 GEMM, 128x128 tile, BK=64, 4 waves, 2-phase double-buffered prefetch.
// A and Bt chunk-XOR swizzled in global memory; LDS linear (global_load_lds),
// ds_read applies the same XOR -> conflict-free (verified 0 in R7 PMC).
// MODE 0: normal store.
// MODE 3: merged K/V projection. Grid y=8: by 0-3 -> K-pack kt[b][h][c][dh^swz]
//         from (Bt,bias)->C; by 4-7 -> V-pack vt[b][h][dh][c^swz] from
//         (Bt2,bias2)->C2. Shared A (ctx).
template <typename TC, int MODE>
__global__ __launch_bounds__(256) void gemm128_k(
    const unsigned short* __restrict__ A, long lda,
    const unsigned short* __restrict__ Bt,
    const float* __restrict__ bias,
    TC* __restrict__ C, long ldc,
    long jsA, long jsW, long jsB, long jsC,
    const unsigned short* __restrict__ Bt2,
    const float* __restrict__ bias2,
    TC* __restrict__ C2)
{
    __shared__ unsigned short As[2][128*64];
    __shared__ unsigned short Bs[2][128*64];

    const int tid = threadIdx.x;
    const int w = tid >> 6, lane = tid & 63;
    const long j = blockIdx.z;

    // XCD-aware bijective swizzle of the (x,y) grid (nwg % 8 == 0 always here)
    const int nx = gridDim.x;
    const int nwg = nx * gridDim.y;
    int lin = blockIdx.y * nx + blockIdx.x;
    lin = (lin & 7) * (nwg >> 3) + (lin >> 3);
    const int bx = lin % nx, by = lin / nx;

    int kv = 0;        // 1 = K-pack, 2 = V-pack (MODE 3 epilogue select)
    int byv = by;
    if constexpr (MODE == 3) {
        if (by >= 4) { kv = 2; byv = by - 4; Bt = Bt2; bias = bias2; C = C2; }
        else         { kv = 1; }
    }

    A    += (long)bx * 128 * lda + j * jsA;
    Bt   += j * jsW + (long)byv * 128 * 512;
    bias += j * jsB + byv * 128;
    if constexpr (MODE == 0)
        C += (long)bx * 128 * ldc + j * jsC + byv * 128;

    const int srow = lane >> 3;
    const int scol = (lane & 7) * 8;
    const unsigned short* Ag = A  + (long)(w*8 + srow) * lda + scol;
    const unsigned short* Bg = Bt + (long)(w*8 + srow) * 512 + scol;

    const int lr = lane & 15, lk = lane >> 4;
    const int wm = w >> 1, wn = w & 1;

    fx4 acc[4][4] = {};

    auto STAGE = [&](int buf, int kt) {
        char* Al = (char*)&As[buf][0] + w * 1024;
        char* Bl = (char*)&Bs[buf][0] + w * 1024;
        #pragma unroll
        for (int it = 0; it < 4; ++it)
            gload16(Ag + (long)it * 32 * lda + kt, Al + it * 4096);
        #pragma unroll
        for (int it = 0; it < 4; ++it)
            gload16(Bg + (long)it * 32 * 512 + kt, Bl + it * 4096);
    };

    auto COMPUTE = [&](int buf) {
        #pragma unroll
        for (int ks = 0; ks < 2; ++ks) {
            const int cha = (ks*4 + lk) ^ (lr & 7);   // same for A and B rows
            s16x8 a[4], b[4];
            #pragma unroll
            for (int m = 0; m < 4; ++m)
                a[m] = *reinterpret_cast<const s16x8*>(&As[buf][(wm*64 + m*16 + lr)*64 + cha*8]);
            #pragma unroll
            for (int n = 0; n < 4; ++n)
                b[n] = *reinterpret_cast<const s16x8*>(&Bs[buf][(wn*64 + n*16 + lr)*64 + cha*8]);
            #pragma unroll
            for (int m = 0; m < 4; ++m)
                #pragma unroll
                for (int n = 0; n < 4; ++n)
                    acc[m][n] = mfma16(a[m], b[n], acc[m][n]);
        }
    };

    // 2-phase pipeline over 8 K-tiles
    STAGE(0, 0);
    __syncthreads();            // drains vmcnt(0): tile 0 in LDS
    #pragma unroll
    for (int t = 0; t < 7; ++t) {
        const int cur = t & 1;
        STAGE(cur ^ 1, (t + 1) * 64);   // issue next tile's loads first
        COMPUTE(cur);                   // MFMA on current tile hides the loads
        __syncthreads();                // drain next-tile loads + reads of cur
    }
    COMPUTE(1);                 // tile 7

    // epilogue: C/D layout col=lane&15, row=(lane>>4)*4+r
    #pragma unroll
    for (int n = 0; n < 4; ++n) {
        const int col = wn*64 + n*16 + lr;
        const float bv = bias[col];
        #pragma unroll
        for (int m = 0; m < 4; ++m) {
            #pragma unroll
            for (int r = 0; r < 4; ++r) {
                const int row = wm*64 + m*16 + lk*4 + r;
                const float val = acc[m][n][r] + bv;
                if constexpr (MODE == 0) {
                    if constexpr (sizeof(TC) == 2)
                        reinterpret_cast<unsigned short*>(C)[(long)row*ldc + col] = f2bf(val);
                    else
                        reinterpret_cast<float*>(C)[(long)row*ldc + col] = val;
                } else {
                    const int grow = bx*128 + row;       // (b, c)
                    const int gcol = byv*128 + col;      // (h, dh)
                    const int b = grow >> 7, c = grow & 127;
                    const int hh = gcol >> 6, dh = gcol & 63;
                    unsigned short* Cp = reinterpret_cast<unsigned short*>(C);
                    if (kv == 1) {
                        const int dhs = (dh & 7) | ((((dh >> 3) ^ (c & 7)) & 7) << 3);
                        Cp[(((long)b*8 + hh)*128 + c)*64 + dhs] = f2bf(val);
                    } else {
                        const int cs = (c & 7) | ((((c >> 3) ^ (dh & 7)) & 15) << 3);
                        Cp[(((long)b*8 + hh)*64 + dh)*128 + cs] = f2bf(val);
                    }
                }
            }
        }
    }
}

// ---------------------------------------------------------------------------
// Attention v4: 2 q-tiles (2x64 rows) per block, Q direct to registers (no
// Q LDS, no Q barrier), K/V staged once, dedicated P region (Ks stays live
// across both tiles) -> ONE barrier per block. Softmax reductions via DPP
// row_ror (no ds_bpermute latency chains). LDS 48KB -> 3 blocks/CU.
__global__ __launch_bounds__(256, 3) void attn4_k(
    const unsigned short* __restrict__ q,   // bf16 [B, NR, 512] linear
    const unsigned short* __restrict__ kt,  // bf16 [B,H,128,64] swizzled
    const unsigned short* __restrict__ vt,  // bf16 [B,H,64,128] swizzled
    unsigned short* __restrict__ o)         // bf16 [B, NR, 512] GEMM-swizzled
{
    __shared__ __align__(16) unsigned short Ks[128*64];   // K [c][dh] swz
    __shared__ __align__(16) unsigned short Vs[64*128];   // V^T [dh][c] swz
    __shared__ __align__(16) unsigned short Ps[64*128];   // P [t][c] swz

    const int tid = threadIdx.x;
    const int w = tid >> 6, lane = tid & 63;
    const int lr = lane & 15, lk = lane >> 4;
    const int r0 = blockIdx.x * 128;        // 2 tiles of 64 rows
    const int h = blockIdx.y;
    const int b = blockIdx.z;

    // stage K/V (once for both q-tiles)
    const unsigned short* kg = kt + ((long)(b*8+h))*8192 + w*2048 + lane*8;
    const unsigned short* vg = vt + ((long)(b*8+h))*8192 + w*2048 + lane*8;
    #pragma unroll
    for (int it = 0; it < 4; ++it) {
        gload16(kg + it*512, (char*)Ks + w*4096 + it*1024);
        gload16(vg + it*512, (char*)Vs + w*4096 + it*1024);
    }

    // Q fragments for BOTH tiles -> registers (row = r0 + t*64 + w*16 + lr)
    s16x8 qr[2][2];
    #pragma unroll
    for (int t = 0; t < 2; ++t) {
        const unsigned short* qb = q + ((long)b*NR + r0 + t*64 + w*16 + lr)*512 + h*64;
        #pragma unroll
        for (int kk = 0; kk < 2; ++kk)
            qr[t][kk] = *reinterpret_cast<const s16x8*>(qb + kk*32 + lk*8);
    }
    __syncthreads();   // K/V in LDS (drains vmcnt)

    const float SC = 0.125f * 1.44269504088896340736f;   // scale * log2(e)

    #pragma unroll
    for (int t = 0; t < 2; ++t) {
        // ---- S = Q K^T (16 x 128 per wave) ----
        fx4 s[8] = {};
        __builtin_amdgcn_s_setprio(1);
        #pragma unroll
        for (int kk = 0; kk < 2; ++kk) {
            #pragma unroll
            for (int f = 0; f < 8; ++f) {
                const int c = f*16 + lr;
                const int chunk = (kk*4 + lk) ^ (c & 7);
                s16x8 bk = *reinterpret_cast<const s16x8*>(&Ks[c*64 + chunk*8]);
                s[f] = mfma16(qr[t][kk], bk, s[f]);
            }
        }
        __builtin_amdgcn_s_setprio(0);

        // ---- softmax: in-lane + DPP row_ror reductions over 16-lane rows ----
        #pragma unroll
        for (int rr = 0; rr < 4; ++rr) {
            const int row = w*16 + lk*4 + rr;
            float mx = fmaxf(fmaxf(fmaxf(s[0][rr], s[1][rr]), fmaxf(s[2][rr], s[3][rr])),
                             fmaxf(fmaxf(s[4][rr], s[5][rr]), fmaxf(s[6][rr], s[7][rr])));
            mx = fmaxf(mx, ror16<0x128>(mx));   // ror 8
            mx = fmaxf(mx, ror16<0x124>(mx));   // ror 4
            mx = fmaxf(mx, ror16<0x122>(mx));   // ror 2
            mx = fmaxf(mx, ror16<0x121>(mx));   // ror 1
            float p[8]; float sum = 0.f;
            #pragma unroll
            for (int f = 0; f < 8; ++f) {
                p[f] = exp2f((s[f][rr] - mx) * SC);
                sum += p[f];
            }
            sum += ror16<0x128>(sum);
            sum += ror16<0x124>(sum);
            sum += ror16<0x122>(sum);
            sum += ror16<0x121>(sum);
            const float inv = 1.0f / sum;
            #pragma unroll
            for (int f = 0; f < 8; ++f) {
                const int cg = f*16 + lr;
                Ps[row*128 + (((cg >> 3) ^ (row & 7)) << 3) + (cg & 7)] = f2bf(p[f] * inv);
            }
        }
        // no barrier: wave reads back only its own P rows

        // ---- O = P V (16 x 64 per wave, K = 128) ----
        fx4 oacc[4] = {};
        __builtin_amdgcn_s_setprio(1);
        #pragma unroll
        for (int kt4 = 0; kt4 < 4; ++kt4) {
            const int prow = w*16 + lr;
            s16x8 ap = *reinterpret_cast<const s16x8*>(
                &Ps[prow*128 + (((kt4*4 + lk) ^ (prow & 7)) << 3)]);
            #pragma unroll
            for (int bn = 0; bn < 4; ++bn) {
                const int dh = bn*16 + lr;
                const int chunk = (kt4*4 + lk) ^ (dh & 7);
                s16x8 bv = *reinterpret_cast<const s16x8*>(&Vs[dh*128 + chunk*8]);
                oacc[bn] = mfma16(ap, bv, oacc[bn]);
            }
        }
        __builtin_amdgcn_s_setprio(0);

        // ---- store O with GEMM chunk-XOR swizzle ----
        unsigned short* ob = o + ((long)b*NR + r0 + t*64)*512 + h*64;
        #pragma unroll
        for (int bn = 0; bn < 4; ++bn)
            #pragma unroll
            for (int rr = 0; rr < 4; ++rr) {
                const int row = w*16 + lk*4 + rr;
                const int colg = bn*16 + lr;
                const int ch = ((colg >> 3) ^ (row & 7));
                ob[(long)row*512 + ch*8 + (lr & 7)] = f2bf(oacc[bn][rr]);
            }
        // P region reused next tile by the same wave only -> no barrier
    }
}

extern "C" void kernel_launch(void* const* d_in, const int* in_sizes, int n_in,
                              void* d_out, int out_size, void* d_ws, size_t ws_size,
                              hipStream_t stream)
{
    const float* x    = (const float*)d_in[0];
    const float* ctx  = (const float*)d_in[1];
    const float* Wq   = (const float*)d_in[2];
    const float* bq   = (const float*)d_in[3];
    const float* Wk   = (const float*)d_in[4];
    const float* bk   = (const float*)d_in[5];
    const float* Wv   = (const float*)d_in[6];
    const float* bv   = (const float*)d_in[7];
    const float* Wout = (const float*)d_in[8];
    const float* bout = (const float*)d_in[9];
    float* out = (float*)d_out;

    const size_t NX  = (size_t)45056 * 512;   // x / q / o elements
    const size_t NKV = (size_t)4096 * 512;    // ctx / k / v elements
    const size_t NW  = (size_t)512 * 512;     // one weight matrix

    unsigned short* xbf   = (unsigned short*)d_ws;     // also obf (both GEMM-swizzled)
    unsigned short* qbf   = xbf   + NX;                // linear
    unsigned short* cbf   = qbf   + NX;                // ctx bf16, GEMM-swizzled
    unsigned short* ktp   = cbf   + NKV;               // packed swizzled K
    unsigned short* vtp   = ktp   + NKV;               // packed swizzled V^T
    unsigned short* WqT   = vtp   + NKV;               // 22 matrices, [n][k] swizzled
    unsigned short* WkT   = WqT   + 22 * NW;
    unsigned short* WvT   = WkT   + NW;
    unsigned short* WoutT = WvT   + NW;
    unsigned short* obf   = xbf;

    // 1) ALL preprocessing in one launch (weights first, then ctx, then x)
    conv_all_k<<<dim3(13888), 256, 0, stream>>>(
        x, ctx, Wq, Wk, Wv, Wout, xbf, cbf, WqT, WkT, WvT, WoutT);

    // 2) Q projection: per-joint (M=2048 rows, row stride NJ*ND)
    gemm128_k<unsigned short, 0><<<dim3(16, 4, NJ), 256, 0, stream>>>(
        xbf, (long)NJ*ND, WqT, bq, qbf, (long)NJ*ND,
        (long)ND, (long)NW, (long)ND, (long)ND,
        nullptr, nullptr, nullptr);

    // 3) merged K+V projection: M = 4096, grid y=8 (0-3 K-pack, 4-7 V-pack)
    gemm128_k<unsigned short, 3><<<dim3(32, 8, 1), 256, 0, stream>>>(
        cbf, ND, WkT, bk, ktp, ND, 0, 0, 0, 0,
        WvT, bv, vtp);

    // 4) fused attention: one block per (128-row q-pair, h, b)
    attn4_k<<<dim3(NR/128, NH, NB), 256, 0, stream>>>(qbf, ktp, vtp, obf);

    // 5) output projection: bf16 A (pre-swizzled by attn4), f32 output
    gemm128_k<float, 0><<<dim3(45056/128, 4, 1), 256, 0, stream>>>(
        obf, ND, WoutT, bout, out, ND, 0, 0, 0, 0,
        nullptr, nullptr, nullptr);
}